// Round 10
// baseline (676.249 us; speedup 1.0000x reference)
//
#include <hip/hip_runtime.h>

#define TT 256
#define CONDL 192
#define PREDL 64
#define HH 256
#define BB 4096
#define BT 16            // batch tile per block
#define NTHR 512         // 8 waves, 2 per SIMD

#define WSC 2032.0f      // weight scale = 127 / 0.0625 (init bound 1/sqrt(H))
#define HSC 127.0f       // h scale (|h| < 1)
#define SINV (1.0f / (127.0f * 2032.0f))
#define L2E 1.44269504f
// LUT: sigmoid over z in [-16,16), 512 bins, idx = z*16 + 256
#define C16 (SINV * 16.0f)   // acc coeff, sigmoid gates
#define C32 (SINV * 32.0f)   // acc coeff, tanh gate (z doubled)

typedef int i32x4 __attribute__((ext_vector_type(4)));
typedef signed char i8x16 __attribute__((ext_vector_type(16)));
typedef unsigned short u16x4 __attribute__((ext_vector_type(4)));

__device__ __forceinline__ short f2bf(float f) {
  unsigned u = __builtin_bit_cast(unsigned, f);
  unsigned r = (u + 0x7fffu + ((u >> 16) & 1u)) >> 16;
  return (short)r;
}
__device__ __forceinline__ float bf2f(short s) {
  unsigned u = ((unsigned)(unsigned short)s) << 16;
  return __builtin_bit_cast(float, u);
}
__device__ __forceinline__ float sig_(float x) {
  return __builtin_amdgcn_rcpf(1.0f + __builtin_amdgcn_exp2f(-L2E * x));
}

// Pack w_hh [1024][256] fp32 -> int8 B-fragments for mfma_i32_16x16x64_i8.
// frag (jt,kb): lane holds W_q[n = jt*16 + (lane&15)][k = kb*64 + (lane>>4)*16 + j].
__global__ void pack_w(const float* __restrict__ w_hh, signed char* __restrict__ wq) {
  int idx = blockIdx.x * 256 + threadIdx.x;   // (jt*4+kb)*64 + lane
  int lane = idx & 63;
  int kb = (idx >> 6) & 3;
  int jt = idx >> 8;
  int n = jt * 16 + (lane & 15);
  int k0 = kb * 64 + (lane >> 4) * 16;
  i8x16 v;
#pragma unroll
  for (int j = 0; j < 16; ++j)
    v[j] = (signed char)__float2int_rn(w_hh[n * 256 + k0 + j] * WSC);
  *(i8x16*)(wq + (long)idx * 16) = v;
}

__global__ __launch_bounds__(NTHR, 2)
void lstm_main(const float* __restrict__ cd, const float* __restrict__ pred,
               const float* __restrict__ w_ih, const float* __restrict__ b_ih,
               const float* __restrict__ b_hh, const float* __restrict__ w_out,
               const float* __restrict__ b_out, const signed char* __restrict__ wq,
               float* __restrict__ out) {
  // LDS: h dbuf 8 KB (i8 frag order) + x 8 KB + sigmoid LUT 4 KB = 20 KB
  __shared__ __align__(16) signed char h_s[2 * 4096];
  __shared__ __align__(16) short x_s[TT * BT];
  __shared__ __align__(8) float2 tbl[512];   // {sig(z_i), sig(z_{i+1})-sig(z_i)}

  const int tid = threadIdx.x;
  const int lane = tid & 63;
  const int wv = tid >> 6;        // wave 0..7
  const int r0 = blockIdx.x * BT;
  const int lm = lane & 15;
  const int lq = lane >> 4;
  const int m0 = lq * 4;

  // ---- one-time staging ----
  for (int i = tid; i < BT * CONDL; i += NTHR) {
    int r = i / CONDL, t = i % CONDL;
    x_s[t * BT + r] = f2bf(cd[(r0 + r) * CONDL + t]);
  }
  for (int i = tid; i < BT * PREDL; i += NTHR) {
    int r = i / PREDL, t = i % PREDL;
    x_s[(CONDL + t) * BT + r] = f2bf(pred[(r0 + r) * PREDL + t]);
  }
  for (int i = tid; i < 1024; i += NTHR) ((int*)h_s)[i] = 0;  // h_0 = 0, buffer 0

  // sigmoid LUT build: bin i covers z in [i/16-16, (i+1)/16-16)
  {
    float z0 = (float)tid * 0.0625f - 16.0f;
    float s0 = 1.0f / (1.0f + expf(-z0));
    float s1 = 1.0f / (1.0f + expf(-(z0 + 0.0625f)));
    tbl[tid] = make_float2(s0, s1 - s0);
  }

  // ALL 4 gates' weight frags in registers: chain a = g*2+i, 8 x 4 kb = 128 regs.
  const i32x4* wq4 = (const i32x4*)wq;
  i32x4 wrq[32];
#pragma unroll
  for (int a = 0; a < 8; ++a) {
    int jt = (a >> 1) * 16 + wv * 2 + (a & 1);
#pragma unroll
    for (int kb = 0; kb < 4; ++kb)
      wrq[a * 4 + kb] = wq4[(jt * 4 + kb) * 64 + lane];
  }
#pragma unroll
  for (int i = 0; i < 32; ++i) asm volatile("" : "+v"(wrq[i]));

  // Premultiplied index-space constants: idx = acc*Cxx + x*wf_ + bf_
  // sigmoid gates (i,f,o): z*16+256; tanh gate (g): (2z)*16+256.
  float wf_[8], bf_[8];
#pragma unroll
  for (int a = 0; a < 8; ++a) {
    int g = a >> 1;
    int j = g * 256 + (wv * 2 + (a & 1)) * 16 + lm;
    float fac = (g == 2) ? 32.0f : 16.0f;
    wf_[a] = w_ih[j] * fac;
    bf_[a] = (b_ih[j] + b_hh[j]) * fac + 256.0f;
  }

  // h write byte-offset bases (verified R8/R9): base + v*16
  int wbb[2];
#pragma unroll
  for (int i = 0; i < 2; ++i)
    wbb[i] = (wv >> 1) * 1024 + ((wv * 2 + i) & 3) * 256 + lq * 64 + lm;

  float cst[8];   // cell state: subtile i (2) x batch row v (4)
#pragma unroll
  for (int i = 0; i < 8; ++i) cst[i] = 0.f;

  i32x4 zeroi;
  zeroi[0] = 0; zeroi[1] = 0; zeroi[2] = 0; zeroi[3] = 0;

  __syncthreads();

  // ---- recurrence ----
  for (int t = 0; t < TT; ++t) {
    const signed char* hr = h_s + (t & 1) * 4096;
    signed char* hw = h_s + ((t + 1) & 1) * 4096;

    // all 4 A-frags + x up front (5 outstanding LDS reads)
    i32x4 af0 = *(const i32x4*)(hr + 0 * 1024 + lane * 16);
    i32x4 af1 = *(const i32x4*)(hr + 1 * 1024 + lane * 16);
    i32x4 af2 = *(const i32x4*)(hr + 2 * 1024 + lane * 16);
    i32x4 af3 = *(const i32x4*)(hr + 3 * 1024 + lane * 16);
    u16x4 xq = *(const u16x4*)(x_s + t * BT + m0);

    float xr[4];
#pragma unroll
    for (int v = 0; v < 4; ++v) xr[v] = bf2f((short)xq[v]);

    i32x4 acc[8];

#define MQ(AF, KB, ODD)                                                        \
    acc[0 + ODD] = __builtin_amdgcn_mfma_i32_16x16x64_i8(                      \
        AF, wrq[(0 + ODD) * 4 + KB], KB ? acc[0 + ODD] : zeroi, 0, 0, 0);      \
    acc[2 + ODD] = __builtin_amdgcn_mfma_i32_16x16x64_i8(                      \
        AF, wrq[(2 + ODD) * 4 + KB], KB ? acc[2 + ODD] : zeroi, 0, 0, 0);      \
    acc[4 + ODD] = __builtin_amdgcn_mfma_i32_16x16x64_i8(                      \
        AF, wrq[(4 + ODD) * 4 + KB], KB ? acc[4 + ODD] : zeroi, 0, 0, 0);      \
    acc[6 + ODD] = __builtin_amdgcn_mfma_i32_16x16x64_i8(                      \
        AF, wrq[(6 + ODD) * 4 + KB], KB ? acc[6 + ODD] : zeroi, 0, 0, 0);

    // sigmoid via LUT+lerp: Y = tbl[i].x + frac*tbl[i].y, i = clamp(F,0,511)
#define LUT(Y, F)                                                              \
    float Y;                                                                   \
    {                                                                          \
      float cl_ = __builtin_amdgcn_fmed3f((F), 0.0f, 511.0f);                  \
      int i_ = (int)cl_;                                                       \
      float2 e_ = tbl[i_];                                                     \
      Y = fmaf(cl_ - (float)i_, e_.y, e_.x);                                   \
    }

    // ELEM for one cell: 5 lookups, zero transcendentals.
#define ELEMC(I, V)                                                            \
    {                                                                          \
      float aI = (float)acc[0 + I][V];                                         \
      float aF = (float)acc[2 + I][V];                                         \
      float aG = (float)acc[4 + I][V];                                         \
      float aO = (float)acc[6 + I][V];                                         \
      float xi = xr[V];                                                        \
      float fI = fmaf(aI, C16, fmaf(xi, wf_[0 + I], bf_[0 + I]));              \
      float fF = fmaf(aF, C16, fmaf(xi, wf_[2 + I], bf_[2 + I]));              \
      float fG = fmaf(aG, C32, fmaf(xi, wf_[4 + I], bf_[4 + I]));              \
      float fO = fmaf(aO, C16, fmaf(xi, wf_[6 + I], bf_[6 + I]));              \
      LUT(ig, fI) LUT(fg, fF) LUT(yg, fG) LUT(og, fO)                          \
      float gg = fmaf(2.0f, yg, -1.0f);                                        \
      float cn = fmaf(fg, cst[I * 4 + V], ig * gg);                            \
      cst[I * 4 + V] = cn;                                                     \
      LUT(yc, fmaf(cn, 32.0f, 256.0f))                                         \
      float h127 = og * fmaf(254.0f, yc, -127.0f);                             \
      hw[wbb[I] + V * 16] = (signed char)__float2int_rn(h127);                 \
    }

    // phase A: subtile-0 chains complete first
    MQ(af0, 0, 0) MQ(af1, 1, 0) MQ(af2, 2, 0) MQ(af3, 3, 0)
    // phase B: subtile-1 MFMAs interleaved with ELEM(subtile 0)
    MQ(af0, 0, 1) ELEMC(0, 0)
    MQ(af1, 1, 1) ELEMC(0, 1)
    MQ(af2, 2, 1) ELEMC(0, 2)
    MQ(af3, 3, 1) ELEMC(0, 3)
    // phase C: ELEM(subtile 1)
    ELEMC(1, 0) ELEMC(1, 1) ELEMC(1, 2) ELEMC(1, 3)

#undef MQ
#undef LUT
#undef ELEMC
    __syncthreads();
  }

  // ---- readout: out[r] = sigmoid(h_last . w_out + b_out); buffer 0 (T even) ----
  const signed char* hf = h_s;
  float bo = b_out[0];
#pragma unroll
  for (int rr = 0; rr < 2; ++rr) {
    int row = wv * 2 + rr;
    float p = 0.f;
#pragma unroll
    for (int c = 0; c < 4; ++c) {
      int k = lane + c * 64;
      int idx = c * 1024 + ((lane >> 4) & 3) * 256 + row * 16 + (lane & 15);
      p += (float)hf[idx] * w_out[k];
    }
#pragma unroll
    for (int off = 32; off > 0; off >>= 1) p += __shfl_down(p, off);
    if (lane == 0) out[r0 + row] = sig_(p * (1.0f / HSC) + bo);
  }
}

extern "C" void kernel_launch(void* const* d_in, const int* in_sizes, int n_in,
                              void* d_out, int out_size, void* d_ws, size_t ws_size,
                              hipStream_t stream) {
  const float* cd    = (const float*)d_in[0];
  const float* pr    = (const float*)d_in[1];
  const float* w_ih  = (const float*)d_in[2];
  const float* w_hh  = (const float*)d_in[3];
  const float* b_ih  = (const float*)d_in[4];
  const float* b_hh  = (const float*)d_in[5];
  const float* w_out = (const float*)d_in[6];
  const float* b_out = (const float*)d_in[7];
  float* out = (float*)d_out;
  signed char* wp = (signed char*)d_ws;   // 256 KB packed int8 weights

  pack_w<<<64, 256, 0, stream>>>(w_hh, wp);
  lstm_main<<<256, NTHR, 0, stream>>>(cd, pr, w_ih, b_ih, b_hh, w_out, b_out, wp, out);
}

// Round 11
// 451.648 us; speedup vs baseline: 1.4973x; 1.4973x over previous
//
#include <hip/hip_runtime.h>

#define TT 256
#define CONDL 192
#define PREDL 64
#define HH 256
#define BB 4096
#define BT 16            // batch tile per block
#define NTHR 512         // 8 waves, 2 per SIMD

#define WSC 2032.0f      // weight scale = 127 / 0.0625 (init bound 1/sqrt(H))
#define HSC 127.0f       // h scale (|h| < 1)
#define SINV (1.0f / (127.0f * 2032.0f))
#define L2E 1.44269504f
#define CSX (-L2E * SINV)        // sigmoid gates: eX = exp2(CSX*acc + arg) = e^-z
#define CGX (2.0f * L2E * SINV)  // tanh gate:     eG = exp2(CGX*acc + arg) = e^{2z}

typedef int i32x4 __attribute__((ext_vector_type(4)));
typedef signed char i8x16 __attribute__((ext_vector_type(16)));
typedef unsigned short u16x4 __attribute__((ext_vector_type(4)));

__device__ __forceinline__ short f2bf(float f) {
  unsigned u = __builtin_bit_cast(unsigned, f);
  unsigned r = (u + 0x7fffu + ((u >> 16) & 1u)) >> 16;
  return (short)r;
}
__device__ __forceinline__ float bf2f(short s) {
  unsigned u = ((unsigned)(unsigned short)s) << 16;
  return __builtin_bit_cast(float, u);
}
__device__ __forceinline__ float sig_(float x) {
  return __builtin_amdgcn_rcpf(1.0f + __builtin_amdgcn_exp2f(-L2E * x));
}

// Pack w_hh [1024][256] fp32 -> int8 B-fragments for mfma_i32_16x16x64_i8.
// frag (jt,kb): lane holds W_q[n = jt*16 + (lane&15)][k = kb*64 + (lane>>4)*16 + j].
__global__ void pack_w(const float* __restrict__ w_hh, signed char* __restrict__ wq) {
  int idx = blockIdx.x * 256 + threadIdx.x;   // (jt*4+kb)*64 + lane
  int lane = idx & 63;
  int kb = (idx >> 6) & 3;
  int jt = idx >> 8;
  int n = jt * 16 + (lane & 15);
  int k0 = kb * 64 + (lane >> 4) * 16;
  i8x16 v;
#pragma unroll
  for (int j = 0; j < 16; ++j)
    v[j] = (signed char)__float2int_rn(w_hh[n * 256 + k0 + j] * WSC);
  *(i8x16*)(wq + (long)idx * 16) = v;
}

__global__ __launch_bounds__(NTHR, 2)
void lstm_main(const float* __restrict__ cd, const float* __restrict__ pred,
               const float* __restrict__ w_ih, const float* __restrict__ b_ih,
               const float* __restrict__ b_hh, const float* __restrict__ w_out,
               const float* __restrict__ b_out, const signed char* __restrict__ wq,
               float* __restrict__ out) {
  // LDS: h dbuf 8 KB (i8 frag order) + x 8 KB = 16 KB. No weight LDS.
  __shared__ __align__(16) signed char h_s[2 * 4096];
  __shared__ __align__(16) short x_s[TT * BT];

  const int tid = threadIdx.x;
  const int lane = tid & 63;
  const int wv = tid >> 6;        // wave 0..7
  const int r0 = blockIdx.x * BT;
  const int lm = lane & 15;
  const int lq = lane >> 4;
  const int m0 = lq * 4;

  // ---- one-time staging ----
  for (int i = tid; i < BT * CONDL; i += NTHR) {
    int r = i / CONDL, t = i % CONDL;
    x_s[t * BT + r] = f2bf(cd[(r0 + r) * CONDL + t]);
  }
  for (int i = tid; i < BT * PREDL; i += NTHR) {
    int r = i / PREDL, t = i % PREDL;
    x_s[(CONDL + t) * BT + r] = f2bf(pred[(r0 + r) * PREDL + t]);
  }
  for (int i = tid; i < 1024; i += NTHR) ((int*)h_s)[i] = 0;  // h_0 = 0, buffer 0

  // ALL 4 gates' weight frags in registers: chain a = g*2+i, 8 x 4 kb = 128 regs.
  const i32x4* wq4 = (const i32x4*)wq;
  i32x4 wrq[32];
#pragma unroll
  for (int a = 0; a < 8; ++a) {
    int jt = (a >> 1) * 16 + wv * 2 + (a & 1);
#pragma unroll
    for (int kb = 0; kb < 4; ++kb)
      wrq[a * 4 + kb] = wq4[(jt * 4 + kb) * 64 + lane];
  }
#pragma unroll
  for (int i = 0; i < 32; ++i) asm volatile("" : "+v"(wrq[i]));

  // Premultiplied f32 gate constants: sigmoid gates carry -log2(e), g carries
  // +2log2(e), so exp2(fma(accf, C, fma(x, wf, bf))) is e^{-z} / e^{2z}.
  float wf_[8], bf_[8];
#pragma unroll
  for (int a = 0; a < 8; ++a) {
    int g = a >> 1;
    int j = g * 256 + (wv * 2 + (a & 1)) * 16 + lm;
    float fac = (g == 2) ? (2.0f * L2E) : -L2E;
    wf_[a] = w_ih[j] * fac;
    bf_[a] = (b_ih[j] + b_hh[j]) * fac;
  }

  // h write byte-offset bases (verified R8/R9): base + v*16
  int wbb[2];
#pragma unroll
  for (int i = 0; i < 2; ++i)
    wbb[i] = (wv >> 1) * 1024 + ((wv * 2 + i) & 3) * 256 + lq * 64 + lm;

  float cst[8];   // cell state: subtile i (2) x batch row v (4)
#pragma unroll
  for (int i = 0; i < 8; ++i) cst[i] = 0.f;

  i32x4 zeroi;
  zeroi[0] = 0; zeroi[1] = 0; zeroi[2] = 0; zeroi[3] = 0;

  __syncthreads();

  // ---- recurrence ----
  for (int t = 0; t < TT; ++t) {
    const signed char* hr = h_s + (t & 1) * 4096;
    signed char* hw = h_s + ((t + 1) & 1) * 4096;

    // all 4 A-frags + x up front (5 outstanding LDS reads)
    i32x4 af0 = *(const i32x4*)(hr + 0 * 1024 + lane * 16);
    i32x4 af1 = *(const i32x4*)(hr + 1 * 1024 + lane * 16);
    i32x4 af2 = *(const i32x4*)(hr + 2 * 1024 + lane * 16);
    i32x4 af3 = *(const i32x4*)(hr + 3 * 1024 + lane * 16);
    u16x4 xq = *(const u16x4*)(x_s + t * BT + m0);

    float xr[4];
#pragma unroll
    for (int v = 0; v < 4; ++v) xr[v] = bf2f((short)xq[v]);

    i32x4 acc[8];

#define MQ(AF, KB, ODD)                                                        \
    acc[0 + ODD] = __builtin_amdgcn_mfma_i32_16x16x64_i8(                      \
        AF, wrq[(0 + ODD) * 4 + KB], KB ? acc[0 + ODD] : zeroi, 0, 0, 0);      \
    acc[2 + ODD] = __builtin_amdgcn_mfma_i32_16x16x64_i8(                      \
        AF, wrq[(2 + ODD) * 4 + KB], KB ? acc[2 + ODD] : zeroi, 0, 0, 0);      \
    acc[4 + ODD] = __builtin_amdgcn_mfma_i32_16x16x64_i8(                      \
        AF, wrq[(4 + ODD) * 4 + KB], KB ? acc[4 + ODD] : zeroi, 0, 0, 0);      \
    acc[6 + ODD] = __builtin_amdgcn_mfma_i32_16x16x64_i8(                      \
        AF, wrq[(6 + ODD) * 4 + KB], KB ? acc[6 + ODD] : zeroi, 0, 0, 0);

    // ELEM, shared-denominator form: 5 exp2 + 2 rcp (was 5 exp2 + 5 rcp).
    // A=1+e^-zi, F=1+e^-zf, G=1+e^{2zg}, O=1+e^-zo:
    //   cn = [c*A*G + (G-2)*F] / (F*A*G)          (ig=1/A, fg=1/F, gg=(G-2)/G)
    //   h  = (C2-2) / (O*C2),  C2 = 1+e^{2*cn}    (og*tanh(cn))
    // Overflow-safe: F*A*G <= 2^95; eC arg clamped to 126 so C2 finite,
    // den2=inf => r2=0 => h=0 (correct og~0 saturation).
#define ELEMC(I, V)                                                            \
    {                                                                          \
      float aI = (float)acc[0 + I][V];                                         \
      float aF = (float)acc[2 + I][V];                                         \
      float aG = (float)acc[4 + I][V];                                         \
      float aO = (float)acc[6 + I][V];                                         \
      float xi = xr[V];                                                        \
      float eI = __builtin_amdgcn_exp2f(fmaf(aI, CSX, fmaf(xi, wf_[0 + I], bf_[0 + I]))); \
      float eF = __builtin_amdgcn_exp2f(fmaf(aF, CSX, fmaf(xi, wf_[2 + I], bf_[2 + I]))); \
      float eG = __builtin_amdgcn_exp2f(fmaf(aG, CGX, fmaf(xi, wf_[4 + I], bf_[4 + I]))); \
      float eO = __builtin_amdgcn_exp2f(fmaf(aO, CSX, fmaf(xi, wf_[6 + I], bf_[6 + I]))); \
      float A_ = 1.0f + eI, F_ = 1.0f + eF, G_ = 1.0f + eG, O_ = 1.0f + eO;    \
      float AG = A_ * G_;                                                      \
      float num = fmaf(G_ - 2.0f, F_, cst[I * 4 + V] * AG);                    \
      float r1 = __builtin_amdgcn_rcpf(F_ * AG);                               \
      float cn = num * r1;                                                     \
      cst[I * 4 + V] = cn;                                                     \
      float eC = __builtin_amdgcn_exp2f(fminf(cn * (2.0f * L2E), 126.0f));     \
      float C2 = 1.0f + eC;                                                    \
      float r2 = __builtin_amdgcn_rcpf(O_ * C2);                               \
      float h127 = fmaf(HSC, C2, -2.0f * HSC) * r2;                            \
      hw[wbb[I] + V * 16] = (signed char)__float2int_rn(h127);                 \
    }

    // phase A: subtile-0 chains complete first
    MQ(af0, 0, 0) MQ(af1, 1, 0) MQ(af2, 2, 0) MQ(af3, 3, 0)
    // phase B: subtile-1 MFMAs interleaved with ELEM(subtile 0)
    MQ(af0, 0, 1) ELEMC(0, 0)
    MQ(af1, 1, 1) ELEMC(0, 1)
    MQ(af2, 2, 1) ELEMC(0, 2)
    MQ(af3, 3, 1) ELEMC(0, 3)
    // phase C: ELEM(subtile 1)
    ELEMC(1, 0) ELEMC(1, 1) ELEMC(1, 2) ELEMC(1, 3)

#undef MQ
#undef ELEMC
    __syncthreads();
  }

  // ---- readout: out[r] = sigmoid(h_last . w_out + b_out); buffer 0 (T even) ----
  const signed char* hf = h_s;
  float bo = b_out[0];
#pragma unroll
  for (int rr = 0; rr < 2; ++rr) {
    int row = wv * 2 + rr;
    float p = 0.f;
#pragma unroll
    for (int c = 0; c < 4; ++c) {
      int k = lane + c * 64;
      int idx = c * 1024 + ((lane >> 4) & 3) * 256 + row * 16 + (lane & 15);
      p += (float)hf[idx] * w_out[k];
    }
#pragma unroll
    for (int off = 32; off > 0; off >>= 1) p += __shfl_down(p, off);
    if (lane == 0) out[r0 + row] = sig_(p * (1.0f / HSC) + bo);
  }
}

extern "C" void kernel_launch(void* const* d_in, const int* in_sizes, int n_in,
                              void* d_out, int out_size, void* d_ws, size_t ws_size,
                              hipStream_t stream) {
  const float* cd    = (const float*)d_in[0];
  const float* pr    = (const float*)d_in[1];
  const float* w_ih  = (const float*)d_in[2];
  const float* w_hh  = (const float*)d_in[3];
  const float* b_ih  = (const float*)d_in[4];
  const float* b_hh  = (const float*)d_in[5];
  const float* w_out = (const float*)d_in[6];
  const float* b_out = (const float*)d_in[7];
  float* out = (float*)d_out;
  signed char* wp = (signed char*)d_ws;   // 256 KB packed int8 weights

  pack_w<<<64, 256, 0, stream>>>(w_hh, wp);
  lstm_main<<<256, NTHR, 0, stream>>>(cd, pr, w_ih, b_ih, b_hh, w_out, b_out, wp, out);
}

// Round 12
// 419.304 us; speedup vs baseline: 1.6128x; 1.0771x over previous
//
#include <hip/hip_runtime.h>

#define TT 256
#define CONDL 192
#define PREDL 64
#define HH 256
#define BB 4096
#define BT 16            // batch tile per block
#define NTHR 1024        // 16 waves, 4 per SIMD

#define WSC 2032.0f      // weight scale = 127 / 0.0625 (init bound 1/sqrt(H))
#define HSC 127.0f       // h scale (|h| < 1)
#define SINV (1.0f / (127.0f * 2032.0f))
#define L2E 1.44269504f
#define CSX (-L2E * SINV)        // sigmoid gates: e = exp2(CSX*acc + arg) = e^-z
#define CGX (2.0f * L2E * SINV)  // tanh gate:     e = exp2(CGX*acc + arg) = e^{2z}

typedef int i32x4 __attribute__((ext_vector_type(4)));
typedef signed char i8x16 __attribute__((ext_vector_type(16)));
typedef unsigned short u16x4 __attribute__((ext_vector_type(4)));

__device__ __forceinline__ short f2bf(float f) {
  unsigned u = __builtin_bit_cast(unsigned, f);
  unsigned r = (u + 0x7fffu + ((u >> 16) & 1u)) >> 16;
  return (short)r;
}
__device__ __forceinline__ float bf2f(short s) {
  unsigned u = ((unsigned)(unsigned short)s) << 16;
  return __builtin_bit_cast(float, u);
}
__device__ __forceinline__ float sig_(float x) {
  return __builtin_amdgcn_rcpf(1.0f + __builtin_amdgcn_exp2f(-L2E * x));
}

// Pack w_hh [1024][256] fp32 -> int8 B-fragments for mfma_i32_16x16x64_i8.
// frag (jt,kb): lane holds W_q[n = jt*16 + (lane&15)][k = kb*64 + (lane>>4)*16 + j].
__global__ void pack_w(const float* __restrict__ w_hh, signed char* __restrict__ wq) {
  int idx = blockIdx.x * 256 + threadIdx.x;   // (jt*4+kb)*64 + lane
  int lane = idx & 63;
  int kb = (idx >> 6) & 3;
  int jt = idx >> 8;
  int n = jt * 16 + (lane & 15);
  int k0 = kb * 64 + (lane >> 4) * 16;
  i8x16 v;
#pragma unroll
  for (int j = 0; j < 16; ++j)
    v[j] = (signed char)__float2int_rn(w_hh[n * 256 + k0 + j] * WSC);
  *(i8x16*)(wq + (long)idx * 16) = v;
}

__global__ __launch_bounds__(NTHR, 4)
void lstm_main(const float* __restrict__ cd, const float* __restrict__ pred,
               const float* __restrict__ w_ih, const float* __restrict__ b_ih,
               const float* __restrict__ b_hh, const float* __restrict__ w_out,
               const float* __restrict__ b_out, const signed char* __restrict__ wq,
               float* __restrict__ out) {
  // LDS: h dbuf 8 KB (i8 frag order) + x 8 KB = 16 KB
  __shared__ __align__(16) signed char h_s[2 * 4096];
  __shared__ __align__(16) short x_s[TT * BT];

  const int tid = threadIdx.x;
  const int lane = tid & 63;
  const int wv = tid >> 6;        // wave 0..15: owns subtile wv (units wv*16+lm)
  const int r0 = blockIdx.x * BT;
  const int lm = lane & 15;
  const int lq = lane >> 4;
  const int m0 = lq * 4;

  // ---- one-time staging ----
  for (int i = tid; i < BT * CONDL; i += NTHR) {
    int r = i / CONDL, t = i % CONDL;
    x_s[t * BT + r] = f2bf(cd[(r0 + r) * CONDL + t]);
  }
  for (int i = tid; i < BT * PREDL; i += NTHR) {
    int r = i / PREDL, t = i % PREDL;
    x_s[(CONDL + t) * BT + r] = f2bf(pred[(r0 + r) * PREDL + t]);
  }
  for (int i = tid; i < 1024; i += NTHR) ((int*)h_s)[i] = 0;  // h_0 = 0, buffer 0

  // Wave's 4 gate-chains for subtile wv: 16 x i32x4 = 64 regs.
  const i32x4* wq4 = (const i32x4*)wq;
  i32x4 wrq[16];
#pragma unroll
  for (int g = 0; g < 4; ++g) {
    int jt = g * 16 + wv;
#pragma unroll
    for (int kb = 0; kb < 4; ++kb)
      wrq[g * 4 + kb] = wq4[(jt * 4 + kb) * 64 + lane];
  }
#pragma unroll
  for (int i = 0; i < 16; ++i) asm volatile("" : "+v"(wrq[i]));

  // Premultiplied f32 gate constants (g carries +2log2e, others -log2e)
  float wf_[4], bf_[4];
#pragma unroll
  for (int g = 0; g < 4; ++g) {
    int j = g * 256 + wv * 16 + lm;
    float fac = (g == 2) ? (2.0f * L2E) : -L2E;
    wf_[g] = w_ih[j] * fac;
    bf_[g] = (b_ih[j] + b_hh[j]) * fac;
  }

  // h write byte base: unit u = wv*16+lm -> kb=wv>>2, sub=wv&3; row r = lq*4+v
  const int wbb = (wv >> 2) * 1024 + (wv & 3) * 256 + lq * 64 + lm;

  float cst[4];   // cell state per batch row v
#pragma unroll
  for (int i = 0; i < 4; ++i) cst[i] = 0.f;

  i32x4 zeroi;
  zeroi[0] = 0; zeroi[1] = 0; zeroi[2] = 0; zeroi[3] = 0;

  __syncthreads();

  // ---- recurrence ----
  for (int t = 0; t < TT; ++t) {
    const signed char* hr = h_s + (t & 1) * 4096;
    signed char* hw = h_s + ((t + 1) & 1) * 4096;

    i32x4 acc[4];   // one chain per gate

    // 1-deep A-frag prefetch; 16 MFMAs total (4 kb x 4 gates)
    i32x4 af_c = *(const i32x4*)(hr + lane * 16);
#pragma unroll
    for (int kb = 0; kb < 4; ++kb) {
      i32x4 af = af_c;
      if (kb < 3) af_c = *(const i32x4*)(hr + (kb + 1) * 1024 + lane * 16);
      acc[0] = __builtin_amdgcn_mfma_i32_16x16x64_i8(
          af, wrq[0 * 4 + kb], kb ? acc[0] : zeroi, 0, 0, 0);
      acc[1] = __builtin_amdgcn_mfma_i32_16x16x64_i8(
          af, wrq[1 * 4 + kb], kb ? acc[1] : zeroi, 0, 0, 0);
      acc[2] = __builtin_amdgcn_mfma_i32_16x16x64_i8(
          af, wrq[2 * 4 + kb], kb ? acc[2] : zeroi, 0, 0, 0);
      acc[3] = __builtin_amdgcn_mfma_i32_16x16x64_i8(
          af, wrq[3 * 4 + kb], kb ? acc[3] : zeroi, 0, 0, 0);
    }

    // x_t for this lane's 4 batch rows
    u16x4 xq = *(const u16x4*)(x_s + t * BT + m0);
    float xr[4];
#pragma unroll
    for (int v = 0; v < 4; ++v) xr[v] = bf2f((short)xq[v]);

    // ELEM, shared-denominator form (R11-verified): 5 exp2 + 2 rcp per cell.
#pragma unroll
    for (int v = 0; v < 4; ++v) {
      float aI = (float)acc[0][v];
      float aF = (float)acc[1][v];
      float aG = (float)acc[2][v];
      float aO = (float)acc[3][v];
      float xi = xr[v];
      float eI = __builtin_amdgcn_exp2f(fmaf(aI, CSX, fmaf(xi, wf_[0], bf_[0])));
      float eF = __builtin_amdgcn_exp2f(fmaf(aF, CSX, fmaf(xi, wf_[1], bf_[1])));
      float eG = __builtin_amdgcn_exp2f(fmaf(aG, CGX, fmaf(xi, wf_[2], bf_[2])));
      float eO = __builtin_amdgcn_exp2f(fmaf(aO, CSX, fmaf(xi, wf_[3], bf_[3])));
      float A_ = 1.0f + eI, F_ = 1.0f + eF, G_ = 1.0f + eG, O_ = 1.0f + eO;
      float AG = A_ * G_;
      float num = fmaf(G_ - 2.0f, F_, cst[v] * AG);
      float r1 = __builtin_amdgcn_rcpf(F_ * AG);
      float cn = num * r1;
      cst[v] = cn;
      float eC = __builtin_amdgcn_exp2f(fminf(cn * (2.0f * L2E), 126.0f));
      float C2 = 1.0f + eC;
      float r2 = __builtin_amdgcn_rcpf(O_ * C2);
      float h127 = fmaf(HSC, C2, -2.0f * HSC) * r2;
      hw[wbb + v * 16] = (signed char)__float2int_rn(h127);
    }
    __syncthreads();
  }

  // ---- readout: out[r] = sigmoid(h_last . w_out + b_out); buffer 0 (T even) ----
  const signed char* hf = h_s;
  float bo = b_out[0];
  {
    int row = wv;   // 16 waves, one batch row each
    float p = 0.f;
#pragma unroll
    for (int c = 0; c < 4; ++c) {
      int k = lane + c * 64;
      int idx = c * 1024 + ((lane >> 4) & 3) * 256 + row * 16 + (lane & 15);
      p += (float)hf[idx] * w_out[k];
    }
#pragma unroll
    for (int off = 32; off > 0; off >>= 1) p += __shfl_down(p, off);
    if (lane == 0) out[r0 + row] = sig_(p * (1.0f / HSC) + bo);
  }
}

extern "C" void kernel_launch(void* const* d_in, const int* in_sizes, int n_in,
                              void* d_out, int out_size, void* d_ws, size_t ws_size,
                              hipStream_t stream) {
  const float* cd    = (const float*)d_in[0];
  const float* pr    = (const float*)d_in[1];
  const float* w_ih  = (const float*)d_in[2];
  const float* w_hh  = (const float*)d_in[3];
  const float* b_ih  = (const float*)d_in[4];
  const float* b_hh  = (const float*)d_in[5];
  const float* w_out = (const float*)d_in[6];
  const float* b_out = (const float*)d_in[7];
  float* out = (float*)d_out;
  signed char* wp = (signed char*)d_ws;   // 256 KB packed int8 weights

  pack_w<<<64, 256, 0, stream>>>(w_hh, wp);
  lstm_main<<<256, NTHR, 0, stream>>>(cd, pr, w_ih, b_ih, b_hh, w_out, b_out, wp, out);
}